// Round 1
// baseline (363.099 us; speedup 1.0000x reference)
//
#include <hip/hip_runtime.h>
#include <hip/hip_bf16.h>

// MHA fwd: B=2, S=2048, D=1024, H=16, HD=64. fp32 in/out, bf16 MFMA internals.
// Pipeline: cast x -> bf16 ; transpose+cast weights ; QKV GEMM (bf16 MFMA) ->
// [B,H,S,HD] ; flash attention (online softmax, causal) -> [B,S,D] bf16 ;
// output projection GEMM -> fp32 + bias.

typedef __bf16 bf16x8 __attribute__((ext_vector_type(8)));
typedef float f32x4 __attribute__((ext_vector_type(4)));

#define S_LEN 2048
#define DMODEL 1024
#define NHEAD 16
#define HDIM 64
#define MROWS 4096  // B*S

// ---------------- cast x (fp32 -> bf16), 4 elems/thread ----------------
__global__ void cast_x_kernel(const float* __restrict__ X, __bf16* __restrict__ Xb) {
    int i = (blockIdx.x * blockDim.x + threadIdx.x) * 4;
    float4 f = *(const float4*)&X[i];
    Xb[i + 0] = (__bf16)f.x;
    Xb[i + 1] = (__bf16)f.y;
    Xb[i + 2] = (__bf16)f.z;
    Xb[i + 3] = (__bf16)f.w;
}

// ---------------- transpose + cast weight: WT[n][k] = W[k][n] ----------------
__global__ void transpose_cast_kernel(const float* __restrict__ W, __bf16* __restrict__ WT) {
    __shared__ float tile[32][33];
    int bx = blockIdx.x, by = blockIdx.y;
    int tx = threadIdx.x;
    for (int i = threadIdx.y; i < 32; i += 8)
        tile[i][tx] = W[(size_t)(by * 32 + i) * DMODEL + bx * 32 + tx];
    __syncthreads();
    for (int i = threadIdx.y; i < 32; i += 8)
        WT[(size_t)(bx * 32 + i) * DMODEL + by * 32 + tx] = (__bf16)tile[tx][i];
}

// ---------------- GEMM 128x128 tile, BK=32, bf16 MFMA 16x16x32 ----------------
// A: [4096][1024] bf16 row-major. Bt: [N][K] bf16 (transposed weight).
// Epilogue QKV: out[n-head layout] bf16.  Epilogue OUT: fp32 row-major + bias.
#define LDT 40  // padded LDS row (bf16): 80 B -> 16B aligned, 2-way banks (free)

__global__ __launch_bounds__(256) void gemm_qkv_kernel(
    const __bf16* __restrict__ X,
    const __bf16* __restrict__ WqT, const __bf16* __restrict__ WkT, const __bf16* __restrict__ WvT,
    const float* __restrict__ bq, const float* __restrict__ bk, const float* __restrict__ bv,
    __bf16* __restrict__ Q, __bf16* __restrict__ K, __bf16* __restrict__ V) {
    const int which = blockIdx.z;
    const __bf16* Bt = (which == 0) ? WqT : (which == 1) ? WkT : WvT;
    const float* bias = (which == 0) ? bq : (which == 1) ? bk : bv;
    __bf16* Out = (which == 0) ? Q : (which == 1) ? K : V;

    __shared__ __bf16 As[128 * LDT];
    __shared__ __bf16 Bs[128 * LDT];

    const int tid = threadIdx.x;
    const int lane = tid & 63;
    const int wave = tid >> 6;
    const int wm = wave >> 1, wn = wave & 1;
    const int quad = lane >> 4;
    const int l16 = lane & 15;
    const int m0 = blockIdx.y * 128;
    const int n0 = blockIdx.x * 128;
    const int lrow = tid >> 2;
    const int lcol = (tid & 3) * 8;

    f32x4 acc[4][4] = {};

    for (int k0 = 0; k0 < DMODEL; k0 += 32) {
        __syncthreads();
        *(bf16x8*)&As[lrow * LDT + lcol]        = *(const bf16x8*)&X[(m0 + lrow) * DMODEL + k0 + lcol];
        *(bf16x8*)&As[(lrow + 64) * LDT + lcol] = *(const bf16x8*)&X[(m0 + lrow + 64) * DMODEL + k0 + lcol];
        *(bf16x8*)&Bs[lrow * LDT + lcol]        = *(const bf16x8*)&Bt[(n0 + lrow) * DMODEL + k0 + lcol];
        *(bf16x8*)&Bs[(lrow + 64) * LDT + lcol] = *(const bf16x8*)&Bt[(n0 + lrow + 64) * DMODEL + k0 + lcol];
        __syncthreads();
        bf16x8 af[4], bfr[4];
#pragma unroll
        for (int t = 0; t < 4; t++) {
            af[t]  = *(bf16x8*)&As[(wm * 64 + t * 16 + l16) * LDT + quad * 8];
            bfr[t] = *(bf16x8*)&Bs[(wn * 64 + t * 16 + l16) * LDT + quad * 8];
        }
#pragma unroll
        for (int mt = 0; mt < 4; mt++)
#pragma unroll
            for (int nt = 0; nt < 4; nt++)
                acc[mt][nt] = __builtin_amdgcn_mfma_f32_16x16x32_bf16(af[mt], bfr[nt], acc[mt][nt], 0, 0, 0);
    }

    // C/D layout: col = lane&15, row = quad*4 + reg  [m89-verified]
#pragma unroll
    for (int mt = 0; mt < 4; mt++)
#pragma unroll
        for (int nt = 0; nt < 4; nt++)
#pragma unroll
            for (int r = 0; r < 4; r++) {
                int m = m0 + wm * 64 + mt * 16 + quad * 4 + r;
                int n = n0 + wn * 64 + nt * 16 + l16;
                float val = acc[mt][nt][r] + bias[n];
                int b = m >> 11, s = m & 2047;
                int h = n >> 6, hd = n & 63;
                Out[(((size_t)(b * NHEAD + h) * S_LEN + s) * HDIM) + hd] = (__bf16)val;
            }
}

__global__ __launch_bounds__(256) void gemm_out_kernel(
    const __bf16* __restrict__ A, const __bf16* __restrict__ Bt,
    const float* __restrict__ bias, float* __restrict__ Y) {
    __shared__ __bf16 As[128 * LDT];
    __shared__ __bf16 Bs[128 * LDT];

    const int tid = threadIdx.x;
    const int lane = tid & 63;
    const int wave = tid >> 6;
    const int wm = wave >> 1, wn = wave & 1;
    const int quad = lane >> 4;
    const int l16 = lane & 15;
    const int m0 = blockIdx.y * 128;
    const int n0 = blockIdx.x * 128;
    const int lrow = tid >> 2;
    const int lcol = (tid & 3) * 8;

    f32x4 acc[4][4] = {};

    for (int k0 = 0; k0 < DMODEL; k0 += 32) {
        __syncthreads();
        *(bf16x8*)&As[lrow * LDT + lcol]        = *(const bf16x8*)&A[(m0 + lrow) * DMODEL + k0 + lcol];
        *(bf16x8*)&As[(lrow + 64) * LDT + lcol] = *(const bf16x8*)&A[(m0 + lrow + 64) * DMODEL + k0 + lcol];
        *(bf16x8*)&Bs[lrow * LDT + lcol]        = *(const bf16x8*)&Bt[(n0 + lrow) * DMODEL + k0 + lcol];
        *(bf16x8*)&Bs[(lrow + 64) * LDT + lcol] = *(const bf16x8*)&Bt[(n0 + lrow + 64) * DMODEL + k0 + lcol];
        __syncthreads();
        bf16x8 af[4], bfr[4];
#pragma unroll
        for (int t = 0; t < 4; t++) {
            af[t]  = *(bf16x8*)&As[(wm * 64 + t * 16 + l16) * LDT + quad * 8];
            bfr[t] = *(bf16x8*)&Bs[(wn * 64 + t * 16 + l16) * LDT + quad * 8];
        }
#pragma unroll
        for (int mt = 0; mt < 4; mt++)
#pragma unroll
            for (int nt = 0; nt < 4; nt++)
                acc[mt][nt] = __builtin_amdgcn_mfma_f32_16x16x32_bf16(af[mt], bfr[nt], acc[mt][nt], 0, 0, 0);
    }

#pragma unroll
    for (int mt = 0; mt < 4; mt++)
#pragma unroll
        for (int nt = 0; nt < 4; nt++)
#pragma unroll
            for (int r = 0; r < 4; r++) {
                int m = m0 + wm * 64 + mt * 16 + quad * 4 + r;
                int n = n0 + wn * 64 + nt * 16 + l16;
                Y[(size_t)m * DMODEL + n] = acc[mt][nt][r] + bias[n];
            }
}

// ---------------- flash attention ----------------
// Block: 256 thr (4 waves). 64-query tile; each wave owns 16 query rows.
// K-tile 64x64 + V^T 64x64 staged in LDS (pad 72); P via per-wave LDS round-trip.
#define LDK 72  // 144 B row: 16B aligned, 2-way banks

__global__ __launch_bounds__(256) void attn_kernel(
    const __bf16* __restrict__ Q, const __bf16* __restrict__ K, const __bf16* __restrict__ V,
    __bf16* __restrict__ Aout) {
    const int qt = blockIdx.x;   // 0..31 query tile
    const int bh = blockIdx.y;   // 0..31 (b*16+h)
    const int b = bh >> 4, h = bh & 15;
    const int tid = threadIdx.x, lane = tid & 63, wave = tid >> 6;
    const int quad = lane >> 4, l16 = lane & 15;

    __shared__ __bf16 Ks[64 * LDK];
    __shared__ __bf16 Vt[64 * LDK];
    __shared__ __bf16 Ps[4][16 * LDK];

    const size_t base = (size_t)bh * S_LEN * HDIM;
    const int q0 = qt * 64;
    const int qrow = q0 + wave * 16 + l16;  // A-frag row (m = lane&15)

    // Q fragments held in registers for the whole block
    bf16x8 qf0 = *(const bf16x8*)&Q[base + (size_t)qrow * HDIM + quad * 8];
    bf16x8 qf1 = *(const bf16x8*)&Q[base + (size_t)qrow * HDIM + 32 + quad * 8];

    float m_old[4], l_old[4];
    f32x4 oacc[4] = {};
#pragma unroll
    for (int r = 0; r < 4; r++) { m_old[r] = -1e30f; l_old[r] = 0.0f; }

    const float scale = 0.125f;  // 1/sqrt(64)

    for (int kt = 0; kt <= qt; kt++) {
        const int k0 = kt * 64;
        __syncthreads();
        {
            int row = tid >> 3;          // 0..31
            int c8 = (tid & 7) * 8;      // 0..56
            *(bf16x8*)&Ks[row * LDK + c8]        = *(const bf16x8*)&K[base + (size_t)(k0 + row) * HDIM + c8];
            *(bf16x8*)&Ks[(row + 32) * LDK + c8] = *(const bf16x8*)&K[base + (size_t)(k0 + row + 32) * HDIM + c8];
            bf16x8 v0 = *(const bf16x8*)&V[base + (size_t)(k0 + row) * HDIM + c8];
            bf16x8 v1 = *(const bf16x8*)&V[base + (size_t)(k0 + row + 32) * HDIM + c8];
#pragma unroll
            for (int j = 0; j < 8; j++) {
                Vt[(c8 + j) * LDK + row]      = v0[j];
                Vt[(c8 + j) * LDK + row + 32] = v1[j];
            }
        }
        __syncthreads();

        // scores: S[16 q][64 k] per wave
        f32x4 sacc[4] = {};
#pragma unroll
        for (int nt = 0; nt < 4; nt++) {
            bf16x8 kf0 = *(bf16x8*)&Ks[(nt * 16 + l16) * LDK + quad * 8];
            bf16x8 kf1 = *(bf16x8*)&Ks[(nt * 16 + l16) * LDK + 32 + quad * 8];
            sacc[nt] = __builtin_amdgcn_mfma_f32_16x16x32_bf16(qf0, kf0, sacc[nt], 0, 0, 0);
            sacc[nt] = __builtin_amdgcn_mfma_f32_16x16x32_bf16(qf1, kf1, sacc[nt], 0, 0, 0);
        }

        const bool diag = (kt == qt);
        float p[4][4];   // [nt][r]
        float rowmax[4], rowsum[4], alpha[4];
#pragma unroll
        for (int r = 0; r < 4; r++) {
            int qg = q0 + wave * 16 + quad * 4 + r;
            float mx = -1e30f;
#pragma unroll
            for (int nt = 0; nt < 4; nt++) {
                float s = sacc[nt][r] * scale;
                if (diag && (k0 + nt * 16 + l16) > qg) s = -1e9f;
                p[nt][r] = s;
                mx = fmaxf(mx, s);
            }
            rowmax[r] = mx;
        }
#pragma unroll
        for (int off = 1; off < 16; off <<= 1)
#pragma unroll
            for (int r = 0; r < 4; r++)
                rowmax[r] = fmaxf(rowmax[r], __shfl_xor(rowmax[r], off, 64));
#pragma unroll
        for (int r = 0; r < 4; r++) {
            float mnew = fmaxf(m_old[r], rowmax[r]);
            alpha[r] = __expf(m_old[r] - mnew);
            float rs = 0.0f;
#pragma unroll
            for (int nt = 0; nt < 4; nt++) {
                float e = __expf(p[nt][r] - mnew);
                p[nt][r] = e;
                rs += e;
            }
            rowsum[r] = rs;
            m_old[r] = mnew;
        }
#pragma unroll
        for (int off = 1; off < 16; off <<= 1)
#pragma unroll
            for (int r = 0; r < 4; r++)
                rowsum[r] += __shfl_xor(rowsum[r], off, 64);
#pragma unroll
        for (int r = 0; r < 4; r++)
            l_old[r] = l_old[r] * alpha[r] + rowsum[r];
#pragma unroll
        for (int nt2 = 0; nt2 < 4; nt2++)
#pragma unroll
            for (int r = 0; r < 4; r++)
                oacc[nt2][r] *= alpha[r];

        // P: C-layout -> A-layout via per-wave LDS round-trip [m120 pattern]
#pragma unroll
        for (int nt = 0; nt < 4; nt++)
#pragma unroll
            for (int r = 0; r < 4; r++)
                Ps[wave][(quad * 4 + r) * LDK + nt * 16 + l16] = (__bf16)p[nt][r];

        bf16x8 pf0 = *(bf16x8*)&Ps[wave][l16 * LDK + quad * 8];
        bf16x8 pf1 = *(bf16x8*)&Ps[wave][l16 * LDK + 32 + quad * 8];
#pragma unroll
        for (int nt2 = 0; nt2 < 4; nt2++) {
            bf16x8 vf0 = *(bf16x8*)&Vt[(nt2 * 16 + l16) * LDK + quad * 8];
            bf16x8 vf1 = *(bf16x8*)&Vt[(nt2 * 16 + l16) * LDK + 32 + quad * 8];
            oacc[nt2] = __builtin_amdgcn_mfma_f32_16x16x32_bf16(pf0, vf0, oacc[nt2], 0, 0, 0);
            oacc[nt2] = __builtin_amdgcn_mfma_f32_16x16x32_bf16(pf1, vf1, oacc[nt2], 0, 0, 0);
        }
    }

    // epilogue: normalize, write merged-head bf16 [B*S][D]
#pragma unroll
    for (int nt2 = 0; nt2 < 4; nt2++)
#pragma unroll
        for (int r = 0; r < 4; r++) {
            int qg = q0 + wave * 16 + quad * 4 + r;
            float o = oacc[nt2][r] / l_old[r];
            int col = h * HDIM + nt2 * 16 + l16;
            Aout[(size_t)(b * S_LEN + qg) * DMODEL + col] = (__bf16)o;
        }
}

extern "C" void kernel_launch(void* const* d_in, const int* in_sizes, int n_in,
                              void* d_out, int out_size, void* d_ws, size_t ws_size,
                              hipStream_t stream) {
    const float* x  = (const float*)d_in[0];
    // d_in[1] = mask: causal triu, reproduced analytically
    const float* wq = (const float*)d_in[2];
    const float* bq = (const float*)d_in[3];
    const float* wk = (const float*)d_in[4];
    const float* bk = (const float*)d_in[5];
    const float* wv = (const float*)d_in[6];
    const float* bv = (const float*)d_in[7];
    const float* wo = (const float*)d_in[8];
    const float* bo = (const float*)d_in[9];
    float* out = (float*)d_out;

    char* ws = (char*)d_ws;
    __bf16* xb  = (__bf16*)(ws);                          // 8 MiB
    __bf16* wqT = (__bf16*)(ws + ((size_t)8  << 20));     // 2 MiB each
    __bf16* wkT = (__bf16*)(ws + ((size_t)10 << 20));
    __bf16* wvT = (__bf16*)(ws + ((size_t)12 << 20));
    __bf16* woT = (__bf16*)(ws + ((size_t)14 << 20));
    __bf16* Qb  = (__bf16*)(ws + ((size_t)16 << 20));     // 8 MiB each
    __bf16* Kb  = (__bf16*)(ws + ((size_t)24 << 20));
    __bf16* Vb  = (__bf16*)(ws + ((size_t)32 << 20));
    __bf16* Ab  = (__bf16*)(ws + ((size_t)40 << 20));     // 8 MiB

    cast_x_kernel<<<4096, 256, 0, stream>>>(x, xb);
    transpose_cast_kernel<<<dim3(32, 32), dim3(32, 8), 0, stream>>>(wq, wqT);
    transpose_cast_kernel<<<dim3(32, 32), dim3(32, 8), 0, stream>>>(wk, wkT);
    transpose_cast_kernel<<<dim3(32, 32), dim3(32, 8), 0, stream>>>(wv, wvT);
    transpose_cast_kernel<<<dim3(32, 32), dim3(32, 8), 0, stream>>>(wo, woT);
    gemm_qkv_kernel<<<dim3(8, 32, 3), 256, 0, stream>>>(xb, wqT, wkT, wvT, bq, bk, bv, Qb, Kb, Vb);
    attn_kernel<<<dim3(32, 32), 256, 0, stream>>>(Qb, Kb, Vb, Ab);
    gemm_out_kernel<<<dim3(8, 32), 256, 0, stream>>>(Ab, woT, bo, out);
}